// Round 5
// baseline (724.075 us; speedup 1.0000x reference)
//
#include <hip/hip_runtime.h>
#include <math.h>

// Problem constants (fixed by setup_inputs)
#define W_ 192
#define H_ 192
#define D_ 160
#define B_ 2
#define HW_ (H_ * W_)

#define TX 32             // output tile x
#define TY 8              // output tile y
#define HY 12             // halo rows (TY + 4)
#define RAWP 41           // raw row stride, 40 data cols + odd stride (<=2-way banks)
#define RSP  33           // rowsum row stride, 32 data cols + odd stride (<=2-way banks)
#define CHUNK 20          // z-planes of output per block
#define PLANES (CHUNK + 4)
#define GX 6              // 192/32
#define GY 24             // 192/8
#define GZ 16             // 8 z-chunks * 2 batches
#define NBLK (GX * GY * GZ)   // 2304
#define NTOT 11796480.0f      // 2*1*160*192*192

__global__ __launch_bounds__(256, 6) void lncc_main(const float* __restrict__ src,
                                                    const float* __restrict__ tgt,
                                                    float* __restrict__ partial) {
    // SoA float LDS, double-buffered for the 1-barrier/plane pipeline.
    // Total 23728 B -> 6 blocks/CU resident.
    __shared__ float rawS[2][HY][RAWP];
    __shared__ float rawT[2][HY][RAWP];
    __shared__ float rsS [2][HY][RSP];
    __shared__ float rsT [2][HY][RSP];
    __shared__ float rsS2[2][HY][RSP];
    __shared__ float rsT2[2][HY][RSP];
    __shared__ float rsST[2][HY][RSP];
    __shared__ float wsum[4];

    const int tid = threadIdx.x;
    const int bz  = blockIdx.z;
    const int b   = bz >> 3;                 // 8 chunks per batch
    const int z0  = (bz & 7) * CHUNK;
    const int bx0 = blockIdx.x * TX - 4;     // raw col 0 <-> gx = bx0 (16B-aligned)
    const int by0 = blockIdx.y * TY - 2;

    // ---- staging decode: tid<120 loads one aligned float4 per array ----
    const int  sr  = tid / 10;               // row 0..11
    const int  sc4 = tid - sr * 10;          // float4 col 0..9
    const int  sc  = sc4 * 4;                // word col 0,4,..,36
    const int  sgx = bx0 + sc;               // multiple of 4 -> float4 aligned
    const int  sgy = by0 + sr;
    const bool sW  = (tid < 120);
    const bool sOk = sW && ((unsigned)sgx < (unsigned)W_) && ((unsigned)sgy < (unsigned)H_);
    const size_t sOff = (size_t)sgy * W_ + (size_t)sgx;   // valid only when sOk

    // ---- phase1 decode: 16 x-pairs x 12 rows = 192 threads, one rep ----
    const int  p0y = tid >> 4;               // row (only tid<192 active)
    const int  xp  = tid & 15;
    const bool pAct = (tid < 192);           // equiv to p0y < HY
    const int  rc  = 2 * xp + 2;             // raw read col base (window of out 2*xp)
    const int  wc  = 2 * xp;                 // rs write col base

    // ---- phase2 decode: thread owns output row y0, column tx ----
    const int tx = tid & 31;                 // 0..31
    const int y0 = tid >> 5;                 // 0..7

    // z-ring as circular buffer. ALL indices are compile-time constants after
    // the full unroll of the plane loop -> pure registers, zero ring-shift movs.
    float qs[5] = {0,0,0,0,0};
    float qt[5] = {0,0,0,0,0};
    float qa[5] = {0,0,0,0,0};
    float qb[5] = {0,0,0,0,0};
    float qc[5] = {0,0,0,0,0};
    float zS=0,zT=0,zA=0,zB=0,zC=0;
    float lsum = 0.0f;

    // phase2: y-sum of rowsums for plane j (buffer rbuf) + z-window + LNCC.
    // Callers pass compile-time rbuf/j (unrolled loop), so j%5 is constant.
    auto phase2 = [&](int rbuf, int j) {
        float yS,yT,yA,yB,yC;
        {
            const float* p = &rsS[rbuf][y0][tx];
            yS = p[0] + p[RSP] + p[2*RSP] + p[3*RSP] + p[4*RSP];
        }
        {
            const float* p = &rsT[rbuf][y0][tx];
            yT = p[0] + p[RSP] + p[2*RSP] + p[3*RSP] + p[4*RSP];
        }
        {
            const float* p = &rsS2[rbuf][y0][tx];
            yA = p[0] + p[RSP] + p[2*RSP] + p[3*RSP] + p[4*RSP];
        }
        {
            const float* p = &rsT2[rbuf][y0][tx];
            yB = p[0] + p[RSP] + p[2*RSP] + p[3*RSP] + p[4*RSP];
        }
        {
            const float* p = &rsST[rbuf][y0][tx];
            yC = p[0] + p[RSP] + p[2*RSP] + p[3*RSP] + p[4*RSP];
        }
        const int sl = j % 5;                // q[sl] holds y from plane j-5
        zS += yS - qs[sl];  zT += yT - qt[sl];  zA += yA - qa[sl];
        zB += yB - qb[sl];  zC += yC - qc[sl];
        qs[sl]=yS; qt[sl]=yT; qa[sl]=yA; qb[sl]=yB; qc[sl]=yC;
        if (j >= 4) {
            const float inv = 1.0f / 125.0f;
            float ms = zS * inv, mt = zT * inv;
            float vs = fmaf(-ms, ms, zA * inv);
            float vt = fmaf(-mt, mt, zB * inv);
            float cr = fmaf(-ms, mt, zC * inv);
            float den = fmaf(vs, vt, 1e-5f);
            lsum = fmaf(cr * cr, __builtin_amdgcn_rcpf(den), lsum);
        }
    };

    // phase1: sliding x-window, 6 raw words -> 2 rowsums per array
    auto rowsum = [&](int buf, int row) {
        const float* pS = &rawS[buf][row][rc];
        const float* pT = &rawT[buf][row][rc];
        float v0=pS[0],v1=pS[1],v2=pS[2],v3=pS[3],v4=pS[4],v5=pS[5];
        float u0=pT[0],u1=pT[1],u2=pT[2],u3=pT[3],u4=pT[4],u5=pT[5];
        float m  = v1 + v2 + v3 + v4;
        float n  = u1 + u2 + u3 + u4;
        float qS = fmaf(v1,v1, fmaf(v2,v2, fmaf(v3,v3, v4*v4)));
        float qT = fmaf(u1,u1, fmaf(u2,u2, fmaf(u3,u3, u4*u4)));
        float qX = fmaf(v1,u1, fmaf(v2,u2, fmaf(v3,u3, v4*u4)));
        rsS [buf][row][wc]   = v0 + m;
        rsS [buf][row][wc+1] = m + v5;
        rsT [buf][row][wc]   = u0 + n;
        rsT [buf][row][wc+1] = n + u5;
        rsS2[buf][row][wc]   = fmaf(v0,v0,qS);
        rsS2[buf][row][wc+1] = fmaf(v5,v5,qS);
        rsT2[buf][row][wc]   = fmaf(u0,u0,qT);
        rsT2[buf][row][wc+1] = fmaf(u5,u5,qT);
        rsST[buf][row][wc]   = fmaf(v0,u0,qX);
        rsST[buf][row][wc+1] = fmaf(v5,u5,qX);
    };

    // ---- prologue: stage plane zp = z0-2 into raw[0] ----
    {
        float4 vS = make_float4(0,0,0,0), vT = make_float4(0,0,0,0);
        const int zp = z0 - 2;
        if (zp >= 0 && sOk) {
            const size_t base = (size_t)(b * D_ + zp) * (size_t)HW_;
            vS = *(const float4*)(src + base + sOff);
            vT = *(const float4*)(tgt + base + sOff);
        }
        if (sW) {
            rawS[0][sr][sc]=vS.x; rawS[0][sr][sc+1]=vS.y; rawS[0][sr][sc+2]=vS.z; rawS[0][sr][sc+3]=vS.w;
            rawT[0][sr][sc]=vT.x; rawT[0][sr][sc+1]=vT.y; rawT[0][sr][sc+2]=vT.z; rawT[0][sr][sc+3]=vT.w;
        }
    }

    #pragma unroll
    for (int i = 0; i < PLANES; ++i) {
        const int buf = i & 1;
        __syncthreads();   // the ONLY barrier per plane
        // -- issue global loads for plane i+1 (consumed at loop end) --
        float4 vS = make_float4(0,0,0,0), vT = make_float4(0,0,0,0);
        const bool haveNext = (i + 1 < PLANES);
        const int  zpn = z0 - 1 + i;
        if (haveNext && zpn >= 0 && zpn < D_ && sOk) {
            const size_t base = (size_t)(b * D_ + zpn) * (size_t)HW_;
            vS = *(const float4*)(src + base + sOff);
            vT = *(const float4*)(tgt + base + sOff);
        }
        // -- phase2 for plane i-1 (rowsums written last iteration) --
        if (i >= 1) phase2(buf ^ 1, i - 1);
        // -- phase1 for plane i: x-rowsums raw[buf] -> rs[buf] --
        if (pAct) rowsum(buf, p0y);
        // -- write staged plane i+1 into raw[buf^1] (vmcnt wait lands here) --
        if (haveNext && sW) {
            rawS[buf^1][sr][sc]=vS.x; rawS[buf^1][sr][sc+1]=vS.y; rawS[buf^1][sr][sc+2]=vS.z; rawS[buf^1][sr][sc+3]=vS.w;
            rawT[buf^1][sr][sc]=vT.x; rawT[buf^1][sr][sc+1]=vT.y; rawT[buf^1][sr][sc+2]=vT.z; rawT[buf^1][sr][sc+3]=vT.w;
        }
    }
    __syncthreads();
    phase2((PLANES - 1) & 1, PLANES - 1);   // drain the pipeline (constants)

    // block reduction -> per-block partial (no atomics, no zero-kernel)
    #pragma unroll
    for (int off = 32; off > 0; off >>= 1)
        lsum += __shfl_down(lsum, off, 64);
    if ((tid & 63) == 0) wsum[tid >> 6] = lsum;
    __syncthreads();
    if (tid == 0) {
        const int bid = (blockIdx.z * GY + blockIdx.y) * GX + blockIdx.x;
        partial[bid] = wsum[0] + wsum[1] + wsum[2] + wsum[3];
    }
}

__global__ __launch_bounds__(256) void lncc_finalize(const float* __restrict__ partial,
                                                     float* __restrict__ out) {
    __shared__ float ws[4];
    const int t = threadIdx.x;
    float s = 0.0f;
    for (int i = t; i < NBLK; i += 256) s += partial[i];
    #pragma unroll
    for (int off = 32; off > 0; off >>= 1) s += __shfl_down(s, off, 64);
    if ((t & 63) == 0) ws[t >> 6] = s;
    __syncthreads();
    if (t == 0) {
        float tot = ws[0] + ws[1] + ws[2] + ws[3];
        float loss = 1.0f - tot * (1.0f / NTOT);
        if (isnan(loss) || isinf(loss)) loss = 1.0f;
        *out = loss;
    }
}

extern "C" void kernel_launch(void* const* d_in, const int* in_sizes, int n_in,
                              void* d_out, int out_size, void* d_ws, size_t ws_size,
                              hipStream_t stream) {
    const float* src = (const float*)d_in[0];
    const float* tgt = (const float*)d_in[1];
    float* out = (float*)d_out;
    float* partial = (float*)d_ws;   // NBLK floats of scratch

    dim3 grid(GX, GY, GZ);           // 6 x 24 x 16 = 2304 blocks
    dim3 block(256, 1, 1);
    lncc_main<<<grid, block, 0, stream>>>(src, tgt, partial);
    lncc_finalize<<<dim3(1), dim3(256), 0, stream>>>(partial, out);
}

// Round 6
// 156.185 us; speedup vs baseline: 4.6360x; 4.6360x over previous
//
#include <hip/hip_runtime.h>
#include <math.h>

// Problem constants (fixed by setup_inputs)
#define W_ 192
#define H_ 192
#define D_ 160
#define B_ 2
#define HW_ (H_ * W_)

#define TX 32             // output tile x
#define TY 8              // output tile y
#define HY 12             // halo rows (TY + 4)
#define RAWP2 42          // raw row stride in float2 (336B = 21*16, b128-aligned rows)
#define RSP2  34          // rs row stride in float2 (272B = 17*16, b128-aligned rows)
#define RSTP  34          // rsST row stride in float (136B = 17*8, b64-aligned rows)
#define CHUNK 20          // z-planes of output per block
#define PLANES (CHUNK + 4)
#define GX 6              // 192/32
#define GY 24             // 192/8
#define GZ 16             // 8 z-chunks * 2 batches
#define NBLK (GX * GY * GZ)   // 2304
#define NTOT 11796480.0f      // 2*1*160*192*192

__device__ __forceinline__ float2 add2(float2 a, float2 b) {
    return make_float2(a.x + b.x, a.y + b.y);   // v_pk_add_f32 candidate
}

__global__ __launch_bounds__(256) void lncc_main(const float* __restrict__ src,
                                                 const float* __restrict__ tgt,
                                                 float* __restrict__ partial) {
    // Packed SoA LDS, double-buffered for the 1-barrier/plane pipeline.
    // rawP = (S,T) interleaved; rsP=(rowsum S, rowsum T); rsQ=(S2,T2); rsST scalar.
    // Total 24400 B -> 6 blocks/CU resident.
    __shared__ __align__(16) float2 rawP[2][HY][RAWP2];
    __shared__ __align__(16) float2 rsP [2][HY][RSP2];
    __shared__ __align__(16) float2 rsQ [2][HY][RSP2];
    __shared__ __align__(16) float  rsST[2][HY][RSTP];
    __shared__ float wsum[4];

    const int tid = threadIdx.x;
    const int bz  = blockIdx.z;
    const int b   = bz >> 3;                 // 8 chunks per batch
    const int z0  = (bz & 7) * CHUNK;
    const int bx0 = blockIdx.x * TX - 4;     // raw col 0 <-> gx = bx0 (16B-aligned)
    const int by0 = blockIdx.y * TY - 2;

    // ---- staging decode: tid<120 loads one aligned float4 per input ----
    const int  sr  = tid / 10;               // row 0..11
    const int  sc4 = tid - sr * 10;          // float4 col 0..9
    const int  sc  = sc4 * 4;                // word col 0,4,..,36 (even, 32B-aligned in rawP)
    const int  sgx = bx0 + sc;               // multiple of 4 -> float4 aligned
    const int  sgy = by0 + sr;
    const bool sW  = (tid < 120);
    const bool sOk = sW && ((unsigned)sgx < (unsigned)W_) && ((unsigned)sgy < (unsigned)H_);
    const size_t sOff = (size_t)sgy * W_ + (size_t)sgx;   // valid only when sOk

    // ---- phase1 decode: 16 x-pairs x 12 rows = 192 threads, one rep ----
    const int  p0y = tid >> 4;               // row (only tid<192 active)
    const int  xp  = tid & 15;
    const bool pAct = (tid < 192);
    const int  rc  = 2 * xp + 2;             // raw read col base (even -> 16B-aligned)
    const int  wc  = 2 * xp;                 // rs write col base (even -> 16B-aligned)

    // ---- phase2 decode: thread owns output row y0, column tx ----
    const int tx = tid & 31;                 // 0..31
    const int y0 = tid >> 5;                 // 0..7

    // z-ring as NAMED scalars (arrays -> scratch: round-4 disaster, rule #20).
    float q0s=0,q0t=0,q0a=0,q0b=0,q0c=0;
    float q1s=0,q1t=0,q1a=0,q1b=0,q1c=0;
    float q2s=0,q2t=0,q2a=0,q2b=0,q2c=0;
    float q3s=0,q3t=0,q3a=0,q3b=0,q3c=0;
    float q4s=0,q4t=0,q4a=0,q4b=0,q4c=0;
    float zS=0,zT=0,zA=0,zB=0,zC=0;
    float lsum = 0.0f;

    // phase2: y-sum of rowsums for plane j (buffer rbuf) + z-window + LNCC
    auto phase2 = [&](int rbuf, int j) {
        float yS,yT,yA,yB,yC;
        {
            const float2* p = &rsP[rbuf][y0][tx];
            float2 ySum = add2(add2(add2(p[0], p[RSP2]), add2(p[2*RSP2], p[3*RSP2])), p[4*RSP2]);
            yS = ySum.x;  yT = ySum.y;
        }
        {
            const float2* p = &rsQ[rbuf][y0][tx];
            float2 ySum = add2(add2(add2(p[0], p[RSP2]), add2(p[2*RSP2], p[3*RSP2])), p[4*RSP2]);
            yA = ySum.x;  yB = ySum.y;
        }
        {
            const float* p = &rsST[rbuf][y0][tx];
            yC = p[0] + p[RSTP] + p[2*RSTP] + p[3*RSTP] + p[4*RSTP];
        }
        zS += yS - q0s;  zT += yT - q0t;  zA += yA - q0a;
        zB += yB - q0b;  zC += yC - q0c;
        q0s=q1s; q0t=q1t; q0a=q1a; q0b=q1b; q0c=q1c;
        q1s=q2s; q1t=q2t; q1a=q2a; q1b=q2b; q1c=q2c;
        q2s=q3s; q2t=q3t; q2a=q3a; q2b=q3b; q2c=q3c;
        q3s=q4s; q3t=q4t; q3a=q4a; q3b=q4b; q3c=q4c;
        q4s=yS;  q4t=yT;  q4a=yA;  q4b=yB;  q4c=yC;
        if (j >= 4) {
            const float inv = 1.0f / 125.0f;
            float ms = zS * inv, mt = zT * inv;
            float vs = fmaf(-ms, ms, zA * inv);
            float vt = fmaf(-mt, mt, zB * inv);
            float cr = fmaf(-ms, mt, zC * inv);
            float den = fmaf(vs, vt, 1e-5f);
            lsum = fmaf(cr * cr, __builtin_amdgcn_rcpf(den), lsum);
        }
    };

    // phase1: sliding x-window on packed (S,T): 3 b128 reads -> 2 rowsums/array
    auto rowsum = [&](int buf, int row) {
        const float4* r4 = (const float4*)&rawP[buf][row][rc];   // 16B-aligned
        float4 A = r4[0], Bv = r4[1], C = r4[2];
        float v0=A.x, u0=A.y, v1=A.z, u1=A.w;
        float v2=Bv.x, u2=Bv.y, v3=Bv.z, u3=Bv.w;
        float v4=C.x, u4=C.y, v5=C.z, u5=C.w;
        float m  = v1 + v2 + v3 + v4;
        float n  = u1 + u2 + u3 + u4;
        float qS = fmaf(v1,v1, fmaf(v2,v2, fmaf(v3,v3, v4*v4)));
        float qT = fmaf(u1,u1, fmaf(u2,u2, fmaf(u3,u3, u4*u4)));
        float qX = fmaf(v1,u1, fmaf(v2,u2, fmaf(v3,u3, v4*u4)));
        // one b128 write per packed array, one b64 for ST
        *(float4*)&rsP[buf][row][wc] =
            make_float4(v0 + m, u0 + n, m + v5, n + u5);
        *(float4*)&rsQ[buf][row][wc] =
            make_float4(fmaf(v0,v0,qS), fmaf(u0,u0,qT), fmaf(v5,v5,qS), fmaf(u5,u5,qT));
        *(float2*)&rsST[buf][row][wc] =
            make_float2(fmaf(v0,u0,qX), fmaf(v5,u5,qX));
    };

    // staging write: two b128 of interleaved (S,T)
    auto stageWrite = [&](int buf, float4 vS, float4 vT) {
        float4* d = (float4*)&rawP[buf][sr][sc];   // sc even -> 16B-aligned
        d[0] = make_float4(vS.x, vT.x, vS.y, vT.y);
        d[1] = make_float4(vS.z, vT.z, vS.w, vT.w);
    };

    // ---- prologue: stage plane zp = z0-2 into raw[0] ----
    {
        float4 vS = make_float4(0,0,0,0), vT = make_float4(0,0,0,0);
        const int zp = z0 - 2;
        if (zp >= 0 && sOk) {
            const size_t base = (size_t)(b * D_ + zp) * (size_t)HW_;
            vS = *(const float4*)(src + base + sOff);
            vT = *(const float4*)(tgt + base + sOff);
        }
        if (sW) stageWrite(0, vS, vT);
    }

    for (int i = 0; i < PLANES; ++i) {
        const int buf = i & 1;
        __syncthreads();   // the ONLY barrier per plane
        // -- issue global loads for plane i+1 (consumed at loop end) --
        float4 vS = make_float4(0,0,0,0), vT = make_float4(0,0,0,0);
        const bool haveNext = (i + 1 < PLANES);
        const int  zpn = z0 - 1 + i;
        if (haveNext && zpn >= 0 && zpn < D_ && sOk) {
            const size_t base = (size_t)(b * D_ + zpn) * (size_t)HW_;
            vS = *(const float4*)(src + base + sOff);
            vT = *(const float4*)(tgt + base + sOff);
        }
        // -- phase2 for plane i-1 (rowsums written last iteration) --
        if (i >= 1) phase2(buf ^ 1, i - 1);
        // -- phase1 for plane i: x-rowsums raw[buf] -> rs[buf] --
        if (pAct) rowsum(buf, p0y);
        // -- write staged plane i+1 into raw[buf^1] (vmcnt wait lands here) --
        if (haveNext && sW) stageWrite(buf ^ 1, vS, vT);
    }
    __syncthreads();
    phase2((PLANES - 1) & 1, PLANES - 1);   // drain the pipeline

    // block reduction -> per-block partial (no atomics, no zero-kernel)
    #pragma unroll
    for (int off = 32; off > 0; off >>= 1)
        lsum += __shfl_down(lsum, off, 64);
    if ((tid & 63) == 0) wsum[tid >> 6] = lsum;
    __syncthreads();
    if (tid == 0) {
        const int bid = (blockIdx.z * GY + blockIdx.y) * GX + blockIdx.x;
        partial[bid] = wsum[0] + wsum[1] + wsum[2] + wsum[3];
    }
}

__global__ __launch_bounds__(256) void lncc_finalize(const float* __restrict__ partial,
                                                     float* __restrict__ out) {
    __shared__ float ws[4];
    const int t = threadIdx.x;
    float s = 0.0f;
    for (int i = t; i < NBLK; i += 256) s += partial[i];
    #pragma unroll
    for (int off = 32; off > 0; off >>= 1) s += __shfl_down(s, off, 64);
    if ((t & 63) == 0) ws[t >> 6] = s;
    __syncthreads();
    if (t == 0) {
        float tot = ws[0] + ws[1] + ws[2] + ws[3];
        float loss = 1.0f - tot * (1.0f / NTOT);
        if (isnan(loss) || isinf(loss)) loss = 1.0f;
        *out = loss;
    }
}

extern "C" void kernel_launch(void* const* d_in, const int* in_sizes, int n_in,
                              void* d_out, int out_size, void* d_ws, size_t ws_size,
                              hipStream_t stream) {
    const float* src = (const float*)d_in[0];
    const float* tgt = (const float*)d_in[1];
    float* out = (float*)d_out;
    float* partial = (float*)d_ws;   // NBLK floats of scratch

    dim3 grid(GX, GY, GZ);           // 6 x 24 x 16 = 2304 blocks
    dim3 block(256, 1, 1);
    lncc_main<<<grid, block, 0, stream>>>(src, tgt, partial);
    lncc_finalize<<<dim3(1), dim3(256), 0, stream>>>(partial, out);
}